// Round 14
// baseline (124.902 us; speedup 1.0000x reference)
//
#include <hip/hip_runtime.h>
#include <math.h>

#define NV 4
#define NB 2
#define NC 32
#define ND 32
#define NH 128
#define NW 160
#define NG 8
#define HW (NH*NW)
#define NPIX (NB*NH*NW)
#define FEATSZ (NV*NB*HW*NC)
#define QMAX 64                // window slots; LDS = 16K (Dsc) + 4K (STl)
#define TBLK (HW/64)
#define TGRID (TBLK*NV*NB)

// ---------------------------------------------------------------------------
// proj setup (tiny, separate launch)
// ---------------------------------------------------------------------------
__global__ void proj_setup_kernel(const float* __restrict__ proj,
                                  float* __restrict__ pw) {
    int t = blockIdx.x * blockDim.x + threadIdx.x;
    if (t >= NB * NV) return;
    int b = t / NV, v = t % NV;
    const float* Eref = proj + ((b*(NV+1) + 0)*2 + 0)*16;
    const float* Kref = proj + ((b*(NV+1) + 0)*2 + 1)*16;
    const float* Esrc = proj + ((b*(NV+1) + (v+1))*2 + 0)*16;
    const float* Ksrc = proj + ((b*(NV+1) + (v+1))*2 + 1)*16;
    float Mr[12], Ms[12];
    for (int i = 0; i < 3; ++i)
        for (int j = 0; j < 4; ++j) {
            float sr = 0.f, ss = 0.f;
            for (int k = 0; k < 3; ++k) {
                sr += Kref[i*4+k] * Eref[k*4+j];
                ss += Ksrc[i*4+k] * Esrc[k*4+j];
            }
            Mr[i*4+j] = sr; Ms[i*4+j] = ss;
        }
    double A[9], a[3];
    for (int i = 0; i < 3; ++i) {
        for (int j = 0; j < 3; ++j) A[i*3+j] = (double)Mr[i*4+j];
        a[i] = (double)Mr[i*4+3];
    }
    double c00 = A[4]*A[8]-A[5]*A[7];
    double c01 = A[5]*A[6]-A[3]*A[8];
    double c02 = A[3]*A[7]-A[4]*A[6];
    double det = A[0]*c00 + A[1]*c01 + A[2]*c02;
    double id  = 1.0/det;
    double Ai[9];
    Ai[0]=c00*id;                 Ai[1]=(A[2]*A[7]-A[1]*A[8])*id; Ai[2]=(A[1]*A[5]-A[2]*A[4])*id;
    Ai[3]=c01*id;                 Ai[4]=(A[0]*A[8]-A[2]*A[6])*id; Ai[5]=(A[2]*A[3]-A[0]*A[5])*id;
    Ai[6]=c02*id;                 Ai[7]=(A[1]*A[6]-A[0]*A[7])*id; Ai[8]=(A[0]*A[4]-A[1]*A[3])*id;
    double R[9], T[3];
    for (int i = 0; i < 3; ++i)
        for (int j = 0; j < 3; ++j) {
            double s = 0.0;
            for (int k = 0; k < 3; ++k) s += (double)Ms[i*4+k] * Ai[k*3+j];
            R[i*3+j] = s;
        }
    for (int i = 0; i < 3; ++i) {
        double s = (double)Ms[i*4+3];
        for (int k = 0; k < 3; ++k) s -= R[i*3+k]*a[k];
        T[i] = s;
    }
    float* o = pw + (b*NV + v)*12;
    for (int i = 0; i < 9; ++i) o[i]   = (float)R[i];
    for (int i = 0; i < 3; ++i) o[9+i] = (float)T[i];
}

// ---------------------------------------------------------------------------
// Prep: src transpose ONLY (ref stays in original layout) + geometry.
// ---------------------------------------------------------------------------
__global__ __launch_bounds__(256) void prep_kernel(
    const float* __restrict__ src_feats,
    const float* __restrict__ depth_hypo,
    const float* __restrict__ pw,
    float* __restrict__ srcT,
    float2* __restrict__ pxpy,
    int4* __restrict__ bboxA)
{
    __shared__ float lds[NC][65];
    int bid = blockIdx.x;
    if (bid < TGRID) {
        int vb = bid / TBLK;
        int hwbase = (bid % TBLK) * 64;
        int t = threadIdx.x;
        #pragma unroll
        for (int r = 0; r < 8; ++r) {
            int c  = (t >> 6) + r*4;
            int hw = t & 63;
            lds[c][hw] = src_feats[(vb*NC + c)*HW + hwbase + hw];
        }
        __syncthreads();
        #pragma unroll
        for (int r = 0; r < 8; ++r) {
            int c  = t & 31;
            int hw = (t >> 5) + r*8;
            srcT[((size_t)vb*HW + hwbase + hw)*NC + c] = lds[c][hw];
        }
        return;
    }
    int tid = (bid - TGRID) * 256 + threadIdx.x;
    int half = tid >> 5;
    int d    = tid & 31;
    if (half >= NV*NPIX) return;
    int v = half / NPIX;
    int p = half - v*NPIX;
    int w = p % NW;
    int h = (p / NW) % NH;
    int b = p / (NW*NH);
    float xf = (float)w, yf = (float)h;
    float depth = depth_hypo[((b*ND + d)*NH + h)*NW + w];

    const float* RT = pw + (b*NV + v)*12;
    double dd  = (double)depth;
    double px_ = ((double)RT[0]*(double)xf + (double)RT[1]*(double)yf + (double)RT[2])*dd + (double)RT[9];
    double py_ = ((double)RT[3]*(double)xf + (double)RT[4]*(double)yf + (double)RT[5])*dd + (double)RT[10];
    double pz_ = ((double)RT[6]*(double)xf + (double)RT[7]*(double)yf + (double)RT[8])*dd + (double)RT[11];
    if (pz_ == 0.0) pz_ = 1e-9;
    double iz  = 1.0 / pz_;
    float valx = (float)(px_*iz);
    float valy = (float)(py_*iz);
    pxpy[(size_t)half*ND + d] = make_float2(valx, valy);

    float fx0 = floorf(valx), fy0 = floorf(valy);
    int x0q = (int)fx0, y0q = (int)fy0;
    int xc0 = min(max(x0q,0),NW-1), xc1 = min(max(x0q+1,0),NW-1);
    int yc0 = min(max(y0q,0),NH-1), yc1 = min(max(y0q+1,0),NH-1);
    int mnx = xc0, mxx = xc1, mny = yc0, mxy = yc1;
    #pragma unroll
    for (int mask = 1; mask < 32; mask <<= 1) {
        mnx = min(mnx, __shfl_xor(mnx, mask, 32));
        mxx = max(mxx, __shfl_xor(mxx, mask, 32));
        mny = min(mny, __shfl_xor(mny, mask, 32));
        mxy = max(mxy, __shfl_xor(mxy, mask, 32));
    }
    if (d == 0) bboxA[half] = make_int4(mnx, mxx, mny, mxy);
}

// ---------------------------------------------------------------------------
// Main: wave = pixel. View pairing {v0,v2 | v1,v3}: half hi stages view
// (hi + 2*vv) — small windows paired with small across halves, large with
// large, balancing the lockstep staging loop. Ref read directly from the
// original [c][hw] layout (4 scalar loads per lane per view). All FP values
// and reduction orders identical to R12.
// ---------------------------------------------------------------------------
__global__ __launch_bounds__(256) void mvs_kernel_g(
    const float* __restrict__ ref_feats,
    const float* __restrict__ srcT,
    const float* __restrict__ depth_hypo,
    const float* __restrict__ w_reg,
    const float2* __restrict__ pxpy,
    const int4* __restrict__ bboxA,
    float* __restrict__ out)
{
    __shared__ float  Dsc[8][QMAX*8];   // 16 KB
    __shared__ float2 STl[8][QMAX];     // 4 KB

    int tid = blockIdx.x * 256 + threadIdx.x;
    int lane = threadIdx.x & 63;
    int d  = lane & 31;
    int hi = lane >> 5;
    int p  = tid >> 6;
    if (p >= NPIX) return;
    int hslot = threadIdx.x >> 5;
    float*  Dh = &Dsc[hslot][0];
    float2* Sh = &STl[hslot][0];
    int sub = lane & 31;
    int jme = sub & 7;

    int w = p % NW;
    int h = (p / NW) % NH;
    int b = p / (NW*NH);
    float depth = depth_hypo[((b*ND + d)*NH + h)*NW + w];

    float wr[NG];
    #pragma unroll
    for (int g = 0; g < NG; ++g) wr[g] = w_reg[g];

    // ---- prefetch both views' geometry (views hi and hi+2) ----
    float2 pvA[2];
    int4   bbA[2];
    {
        size_t h0 = (size_t)hi*NPIX + p;
        size_t h1 = (size_t)(hi+2)*NPIX + p;
        pvA[0] = pxpy[h0*ND + d];
        pvA[1] = pxpy[h1*ND + d];
        bbA[0] = bboxA[h0];
        bbA[1] = bboxA[h1];
    }

    float sv[2], tv[2];

    #pragma unroll
    for (int vv = 0; vv < 2; ++vv) {
        int v = hi + 2*vv;
        float2 pv = pvA[vv];
        int4 bb = bbA[vv];
        float fx0 = floorf(pv.x), fy0 = floorf(pv.y);
        int x0i = (int)fx0, y0i = (int)fy0;
        int x1i = x0i + 1, y1i = y0i + 1;
        float wx = pv.x - fx0, wy = pv.y - fy0;

        float vx0 = (x0i >= 0 && x0i < NW) ? 1.f : 0.f;
        float vx1 = (x1i >= 0 && x1i < NW) ? 1.f : 0.f;
        float vy0 = (y0i >= 0 && y0i < NH) ? 1.f : 0.f;
        float vy1 = (y1i >= 0 && y1i < NH) ? 1.f : 0.f;
        float w00 = (1.f-wx)*(1.f-wy) * vx0*vy0;
        float w01 = wx*(1.f-wy)       * vx1*vy0;
        float w10 = (1.f-wx)*wy       * vx0*vy1;
        float w11 = wx*wy             * vx1*vy1;
        int xc0 = min(max(x0i,0),NW-1), xc1 = min(max(x1i,0),NW-1);
        int yc0 = min(max(y0i,0),NH-1), yc1 = min(max(y1i,0),NH-1);
        int vb = v*NB + b;

        int mnx = bb.x, mny = bb.z;
        int bw = bb.y - mnx + 1;
        int bh = bb.w - mny + 1;
        int U  = bw * bh;

        // ref chunk jme from ORIGINAL layout: 4 scalars at stride HW
        const float* rb = ref_feats + ((size_t)(vb*NC + jme*4))*HW + h*NW + w;
        float s = 0.f, t = 0.f;

        if (U <= QMAX) {
            float4 rfj = make_float4(rb[0], rb[HW], rb[2*HW], rb[3*HW]);
            // ---- phase 1: flattened coalesced element staging ----
            int bw8 = bw * 8;
            int NE  = bh * bw8;
            unsigned int M = (unsigned int)((1u<<22) / (unsigned int)bw8) + 1u;
            int rowstride = NW*NC;
            const float* base = srcT + ((size_t)vb*HW + (size_t)mny*NW + mnx)*NC;
            for (int n = sub; n < NE; n += 32) {
                int row = (int)(((unsigned int)n * M) >> 22);
                int col = n - row*bw8;
                const float4* fp = (const float4*)(base + row*rowstride + col*4);
                float4 f = fp[0];
                float dv = f.x*rfj.x;
                dv = fmaf(f.y, rfj.y, dv);
                dv = fmaf(f.z, rfj.z, dv);
                dv = fmaf(f.w, rfj.w, dv);
                Dh[n] = dv;
            }
            __builtin_amdgcn_wave_barrier();

            // ---- phase 2: compact 8 djs -> (S,T) per q ----
            #pragma unroll
            for (int k = 0; k < 2; ++k) {
                int q = sub + k*32;
                if (q < U) {
                    const float4* dp = (const float4*)&Dh[q*8];
                    float4 a = dp[0], c = dp[1];
                    float S = a.x;  S += a.y;  S += a.z;  S += a.w;
                    S += c.x;  S += c.y;  S += c.z;  S += c.w;
                    float T = wr[0]*a.x;
                    T = fmaf(wr[1], a.y, T);
                    T = fmaf(wr[2], a.z, T);
                    T = fmaf(wr[3], a.w, T);
                    T = fmaf(wr[4], c.x, T);
                    T = fmaf(wr[5], c.y, T);
                    T = fmaf(wr[6], c.z, T);
                    T = fmaf(wr[7], c.w, T);
                    Sh[q] = make_float2(S, T);
                }
            }
            __builtin_amdgcn_wave_barrier();

            // ---- taps ----
            int t00 = (yc0 - mny)*bw + (xc0 - mnx);
            int t01 = (yc0 - mny)*bw + (xc1 - mnx);
            int t10 = (yc1 - mny)*bw + (xc0 - mnx);
            int t11 = (yc1 - mny)*bw + (xc1 - mnx);
            float2 v00 = Sh[t00];
            float2 v01 = Sh[t01];
            float2 v10 = Sh[t10];
            float2 v11 = Sh[t11];
            s = 0.25f*(w00*v00.x + w01*v01.x + w10*v10.x + w11*v11.x);
            t = 0.25f*(w00*v00.y + w01*v01.y + w10*v10.y + w11*v11.y);
        } else {
            // ---- fallback: direct per-depth gathers, ref from original layout ----
            int i00 = yc0*NW+xc0, i01 = yc0*NW+xc1;
            int i10 = yc1*NW+xc0, i11 = yc1*NW+xc1;
            const float4* s00 = (const float4*)(srcT + ((size_t)vb*HW + i00)*NC);
            const float4* s01 = (const float4*)(srcT + ((size_t)vb*HW + i01)*NC);
            const float4* s10 = (const float4*)(srcT + ((size_t)vb*HW + i10)*NC);
            const float4* s11 = (const float4*)(srcT + ((size_t)vb*HW + i11)*NC);
            const float* rbase = ref_feats + (size_t)(vb*NC)*HW + h*NW + w;
            #pragma unroll
            for (int j = 0; j < NG; ++j) {
                float4 a00 = s00[j], a01 = s01[j], a10 = s10[j], a11 = s11[j];
                const float* rj = rbase + (size_t)(j*4)*HW;
                float4 rf = make_float4(rj[0], rj[HW], rj[2*HW], rj[3*HW]);
                float acc = 0.f;
                float f0 = w00*a00.x + w01*a01.x + w10*a10.x + w11*a11.x;
                acc += f0*rf.x;
                float f1 = w00*a00.y + w01*a01.y + w10*a10.y + w11*a11.y;
                acc += f1*rf.y;
                float f2 = w00*a00.z + w01*a01.z + w10*a10.z + w11*a11.z;
                acc += f2*rf.z;
                float f3 = w00*a00.w + w01*a01.w + w10*a10.w + w11*a11.w;
                acc += f3*rf.w;
                float cf = 0.25f*acc;
                s += cf;
                t += cf*wr[j];
            }
        }
        sv[vv] = s; tv[vv] = t;
    }

    // ---- per-view softmax over depths within the half (2-way ILP) ----
    float mv0 = sv[0], mv1 = sv[1];
    #pragma unroll
    for (int mask = 1; mask < 32; mask <<= 1) {
        mv0 = fmaxf(mv0, __shfl_xor(mv0, mask, 32));
        mv1 = fmaxf(mv1, __shfl_xor(mv1, mask, 32));
    }
    float Z0 = expf(sv[0] - mv0);
    float Z1 = expf(sv[1] - mv1);
    #pragma unroll
    for (int mask = 1; mask < 32; mask <<= 1) {
        Z0 += __shfl_xor(Z0, mask, 32);
        Z1 += __shfl_xor(Z1, mask, 32);
    }
    float cwA0 = 1.f / Z0;     // view hi
    float cwA1 = 1.f / Z1;     // view hi+2

    // ---- cross-half exchange; reference-order combine ----
    float cwB0 = __shfl_xor(cwA0, 32, 64);   // view (1-hi)
    float cwB1 = __shfl_xor(cwA1, 32, 64);   // view (1-hi)+2
    float tB0  = __shfl_xor(tv[0], 32, 64);
    float tB1  = __shfl_xor(tv[1], 32, 64);

    float cwv[NV], tvv[NV];
    if (hi == 0) {   // own v0,v2; other half v1,v3
        cwv[0] = cwA0; tvv[0] = tv[0];
        cwv[1] = cwB0; tvv[1] = tB0;
        cwv[2] = cwA1; tvv[2] = tv[1];
        cwv[3] = cwB1; tvv[3] = tB1;
    } else {          // own v1,v3; other half v0,v2
        cwv[0] = cwB0; tvv[0] = tB0;
        cwv[1] = cwA0; tvv[1] = tv[0];
        cwv[2] = cwB1; tvv[2] = tB1;
        cwv[3] = cwA1; tvv[3] = tv[1];
    }
    float logacc = 0.f;
    float cwsum  = 1e-8f;
    #pragma unroll
    for (int v = 0; v < NV; ++v) {
        logacc += cwv[v]*tvv[v];
        cwsum  += cwv[v];
    }

    float logit = logacc / (cwsum + 1e-7f);
    float m2 = logit;
    #pragma unroll
    for (int mask = 1; mask < 32; mask <<= 1)
        m2 = fmaxf(m2, __shfl_xor(m2, mask, 32));
    float e2 = expf(logit - m2);
    float Z2 = e2;
    #pragma unroll
    for (int mask = 1; mask < 32; mask <<= 1)
        Z2 += __shfl_xor(Z2, mask, 32);
    float aw = e2 / Z2;

    float bv2 = aw; int bi = d;
    #pragma unroll
    for (int mask = 1; mask < 32; mask <<= 1) {
        float ov = __shfl_xor(bv2, mask, 32);
        int   oi = __shfl_xor(bi, mask, 32);
        if (ov > bv2 || (ov == bv2 && oi < bi)) { bv2 = ov; bi = oi; }
    }
    float dsel = __shfl(depth, bi, 32);

    if (hi == 0) {
        out[NPIX + ((b*ND + d)*NH + h)*NW + w] = aw;
        if (d == 0) out[p] = dsel;
    }
}

// ---------------------------------------------------------------------------
// Final fallback (original layout) if ws tiny
// ---------------------------------------------------------------------------
__global__ __launch_bounds__(256) void mvs_kernel(
    const float* __restrict__ ref_feats,
    const float* __restrict__ src_feats,
    const float* __restrict__ depth_hypo,
    const float* __restrict__ w_reg,
    const float* __restrict__ pw,
    float* __restrict__ out)
{
    int tid = blockIdx.x * 256 + threadIdx.x;
    int d = threadIdx.x & 31;
    int p = tid >> 5;
    if (p >= NPIX) return;
    int w = p % NW;
    int h = (p / NW) % NH;
    int b = p / (NW*NH);
    float xf = (float)w, yf = (float)h;
    float depth = depth_hypo[((b*ND + d)*NH + h)*NW + w];
    float wr[NG];
    #pragma unroll
    for (int g = 0; g < NG; ++g) wr[g] = w_reg[g];
    float logacc = 0.f;
    float cwsum  = 1e-8f;
    for (int v = 0; v < NV; ++v) {
        const float* RT = pw + (b*NV + v)*12;
        double dd  = (double)depth;
        double px_ = ((double)RT[0]*(double)xf + (double)RT[1]*(double)yf + (double)RT[2])*dd + (double)RT[9];
        double py_ = ((double)RT[3]*(double)xf + (double)RT[4]*(double)yf + (double)RT[5])*dd + (double)RT[10];
        double pz_ = ((double)RT[6]*(double)xf + (double)RT[7]*(double)yf + (double)RT[8])*dd + (double)RT[11];
        if (pz_ == 0.0) pz_ = 1e-9;
        double iz = 1.0/pz_;
        double pxd = px_*iz, pyd = py_*iz;
        double x0d = floor(pxd), y0d = floor(pyd);
        int x0i = (int)x0d, y0i = (int)y0d;
        int x1i = x0i + 1,  y1i = y0i + 1;
        float wx = (float)(pxd - x0d), wy = (float)(pyd - y0d);
        float vx0 = (x0i >= 0 && x0i < NW) ? 1.f : 0.f;
        float vx1 = (x1i >= 0 && x1i < NW) ? 1.f : 0.f;
        float vy0 = (y0i >= 0 && y0i < NH) ? 1.f : 0.f;
        float vy1 = (y1i >= 0 && y1i < NH) ? 1.f : 0.f;
        float w00 = (1.f-wx)*(1.f-wy) * vx0*vy0;
        float w01 = wx*(1.f-wy)       * vx1*vy0;
        float w10 = (1.f-wx)*wy       * vx0*vy1;
        float w11 = wx*wy             * vx1*vy1;
        int xc0 = min(max(x0i,0),NW-1), xc1 = min(max(x1i,0),NW-1);
        int yc0 = min(max(y0i,0),NH-1), yc1 = min(max(y1i,0),NH-1);
        int i00 = yc0*NW+xc0, i01 = yc0*NW+xc1;
        int i10 = yc1*NW+xc0, i11 = yc1*NW+xc1;
        const float* sb = src_feats + ((v*NB + b)*NC)*HW;
        const float* rb = ref_feats + ((v*NB + b)*NC)*HW + h*NW + w;
        float acc[NG];
        #pragma unroll
        for (int g = 0; g < NG; ++g) acc[g] = 0.f;
        #pragma unroll
        for (int c = 0; c < NC; ++c) {
            const float* scp = sb + c*HW;
            float f = w00*scp[i00] + w01*scp[i01] + w10*scp[i10] + w11*scp[i11];
            acc[c>>2] += f * rb[c*HW];
        }
        float s = 0.f, t = 0.f;
        #pragma unroll
        for (int g = 0; g < NG; ++g) {
            float cf = 0.25f*acc[g];
            s += cf;
            t += cf*wr[g];
        }
        float m = s;
        #pragma unroll
        for (int mask = 1; mask < 32; mask <<= 1)
            m = fmaxf(m, __shfl_xor(m, mask, 32));
        float e = expf(s - m);
        float Z = e;
        #pragma unroll
        for (int mask = 1; mask < 32; mask <<= 1)
            Z += __shfl_xor(Z, mask, 32);
        float cw = 1.f / Z;
        logacc += cw * t;
        cwsum  += cw;
    }
    float logit = logacc / (cwsum + 1e-7f);
    float m2 = logit;
    #pragma unroll
    for (int mask = 1; mask < 32; mask <<= 1)
        m2 = fmaxf(m2, __shfl_xor(m2, mask, 32));
    float e2 = expf(logit - m2);
    float Z2 = e2;
    #pragma unroll
    for (int mask = 1; mask < 32; mask <<= 1)
        Z2 += __shfl_xor(Z2, mask, 32);
    float aw = e2 / Z2;
    out[NPIX + ((b*ND + d)*NH + h)*NW + w] = aw;
    float bv = aw; int bi = d;
    #pragma unroll
    for (int mask = 1; mask < 32; mask <<= 1) {
        float ov = __shfl_xor(bv, mask, 32);
        int   oi = __shfl_xor(bi, mask, 32);
        if (ov > bv || (ov == bv && oi < bi)) { bv = ov; bi = oi; }
    }
    float dsel = __shfl(depth, bi, 32);
    if (d == 0) out[p] = dsel;
}

extern "C" void kernel_launch(void* const* d_in, const int* in_sizes, int n_in,
                              void* d_out, int out_size, void* d_ws, size_t ws_size,
                              hipStream_t stream) {
    const float* ref_feats  = (const float*)d_in[0];
    const float* src_feats  = (const float*)d_in[1];
    const float* proj       = (const float*)d_in[2];
    const float* depth_hypo = (const float*)d_in[3];
    const float* w_reg      = (const float*)d_in[4];
    float* out = (float*)d_out;

    size_t featB = (size_t)FEATSZ*sizeof(float);
    size_t geoN  = (size_t)NV*NPIX*ND;
    size_t needG = featB + geoN*sizeof(float2)
                 + (size_t)NV*NPIX*sizeof(int4) + 96*sizeof(float);

    if (ws_size >= needG) {
        char* base = (char*)d_ws;
        float* srcT = (float*)base;                 base += featB;
        float2* pxpy = (float2*)base;               base += geoN*sizeof(float2);
        int4* bboxA = (int4*)base;                  base += (size_t)NV*NPIX*sizeof(int4);
        float* pw = (float*)base;
        hipLaunchKernelGGL(proj_setup_kernel, dim3(1), dim3(64), 0, stream, proj, pw);
        int geoBlocks = (NV*NPIX*32)/256;
        hipLaunchKernelGGL(prep_kernel, dim3(TGRID + geoBlocks), dim3(256), 0, stream,
                           src_feats, depth_hypo, pw, srcT, pxpy, bboxA);
        hipLaunchKernelGGL(mvs_kernel_g, dim3((NPIX*64)/256), dim3(256), 0, stream,
                           ref_feats, srcT, depth_hypo, w_reg, pxpy, bboxA, out);
    } else {
        float* pw = (float*)d_ws;
        hipLaunchKernelGGL(proj_setup_kernel, dim3(1), dim3(64), 0, stream, proj, pw);
        hipLaunchKernelGGL(mvs_kernel, dim3((NPIX*ND)/256), dim3(256), 0, stream,
                           ref_feats, src_feats, depth_hypo, w_reg, pw, out);
    }
}

// Round 15
// 110.879 us; speedup vs baseline: 1.1265x; 1.1265x over previous
//
#include <hip/hip_runtime.h>
#include <math.h>

#define NV 4
#define NB 2
#define NC 32
#define ND 32
#define NH 128
#define NW 160
#define NG 8
#define HW (NH*NW)
#define NPIX (NB*NH*NW)
#define FEATSZ (NV*NB*HW*NC)
#define QMAX 64                // window slots; LDS = 16K (Dsc) + 4K (STl)
#define TBLK (HW/64)
#define TGRID (TBLK*NV*NB)

// ---------------------------------------------------------------------------
// proj setup (tiny, separate launch) — P = K3@E_src @ inv(K3@E_ref), f64 inverse
// ---------------------------------------------------------------------------
__global__ void proj_setup_kernel(const float* __restrict__ proj,
                                  float* __restrict__ pw) {
    int t = blockIdx.x * blockDim.x + threadIdx.x;
    if (t >= NB * NV) return;
    int b = t / NV, v = t % NV;
    const float* Eref = proj + ((b*(NV+1) + 0)*2 + 0)*16;
    const float* Kref = proj + ((b*(NV+1) + 0)*2 + 1)*16;
    const float* Esrc = proj + ((b*(NV+1) + (v+1))*2 + 0)*16;
    const float* Ksrc = proj + ((b*(NV+1) + (v+1))*2 + 1)*16;
    float Mr[12], Ms[12];
    for (int i = 0; i < 3; ++i)
        for (int j = 0; j < 4; ++j) {
            float sr = 0.f, ss = 0.f;
            for (int k = 0; k < 3; ++k) {
                sr += Kref[i*4+k] * Eref[k*4+j];
                ss += Ksrc[i*4+k] * Esrc[k*4+j];
            }
            Mr[i*4+j] = sr; Ms[i*4+j] = ss;
        }
    double A[9], a[3];
    for (int i = 0; i < 3; ++i) {
        for (int j = 0; j < 3; ++j) A[i*3+j] = (double)Mr[i*4+j];
        a[i] = (double)Mr[i*4+3];
    }
    double c00 = A[4]*A[8]-A[5]*A[7];
    double c01 = A[5]*A[6]-A[3]*A[8];
    double c02 = A[3]*A[7]-A[4]*A[6];
    double det = A[0]*c00 + A[1]*c01 + A[2]*c02;
    double id  = 1.0/det;
    double Ai[9];
    Ai[0]=c00*id;                 Ai[1]=(A[2]*A[7]-A[1]*A[8])*id; Ai[2]=(A[1]*A[5]-A[2]*A[4])*id;
    Ai[3]=c01*id;                 Ai[4]=(A[0]*A[8]-A[2]*A[6])*id; Ai[5]=(A[2]*A[3]-A[0]*A[5])*id;
    Ai[6]=c02*id;                 Ai[7]=(A[1]*A[6]-A[0]*A[7])*id; Ai[8]=(A[0]*A[4]-A[1]*A[3])*id;
    double R[9], T[3];
    for (int i = 0; i < 3; ++i)
        for (int j = 0; j < 3; ++j) {
            double s = 0.0;
            for (int k = 0; k < 3; ++k) s += (double)Ms[i*4+k] * Ai[k*3+j];
            R[i*3+j] = s;
        }
    for (int i = 0; i < 3; ++i) {
        double s = (double)Ms[i*4+3];
        for (int k = 0; k < 3; ++k) s -= R[i*3+k]*a[k];
        T[i] = s;
    }
    float* o = pw + (b*NV + v)*12;
    for (int i = 0; i < 9; ++i) o[i]   = (float)R[i];
    for (int i = 0; i < 3; ++i) o[9+i] = (float)T[i];
}

// ---------------------------------------------------------------------------
// Prep: src transpose ONLY ([vb][c][hw] -> [vb][hw][c])
// ---------------------------------------------------------------------------
__global__ __launch_bounds__(256) void prep_kernel(
    const float* __restrict__ src_feats,
    float* __restrict__ srcT)
{
    __shared__ float lds[NC][65];
    int bid = blockIdx.x;
    int vb = bid / TBLK;
    int hwbase = (bid % TBLK) * 64;
    int t = threadIdx.x;
    #pragma unroll
    for (int r = 0; r < 8; ++r) {
        int c  = (t >> 6) + r*4;
        int hw = t & 63;
        lds[c][hw] = src_feats[(vb*NC + c)*HW + hwbase + hw];
    }
    __syncthreads();
    #pragma unroll
    for (int r = 0; r < 8; ++r) {
        int c  = t & 31;
        int hw = (t >> 5) + r*8;
        srcT[((size_t)vb*HW + hwbase + hw)*NC + c] = lds[c][hw];
    }
}

// ---------------------------------------------------------------------------
// Main: wave = pixel; half hi owns views {hi, hi+2} (balanced pairing).
// Geometry computed IN-MAIN in f32 (rotation part is depth-independent;
// per-lane: 3 FMA + rcp + muls + floor). Bbox via 32-lane butterfly from the
// same f32 values -> tap containment by construction. Staging/compaction/
// taps/softmax/combine identical to R13.
// ---------------------------------------------------------------------------
__global__ __launch_bounds__(256) void mvs_kernel_g(
    const float* __restrict__ ref_feats,
    const float* __restrict__ srcT,
    const float* __restrict__ depth_hypo,
    const float* __restrict__ w_reg,
    const float* __restrict__ pw,
    float* __restrict__ out)
{
    __shared__ float  Dsc[8][QMAX*8];   // 16 KB
    __shared__ float2 STl[8][QMAX];     // 4 KB

    int tid = blockIdx.x * 256 + threadIdx.x;
    int lane = threadIdx.x & 63;
    int d  = lane & 31;
    int hi = lane >> 5;
    int p  = tid >> 6;
    if (p >= NPIX) return;
    int hslot = threadIdx.x >> 5;
    float*  Dh = &Dsc[hslot][0];
    float2* Sh = &STl[hslot][0];
    int sub = lane & 31;
    int jme = sub & 7;

    int w = p % NW;
    int h = (p / NW) % NH;
    int b = p / (NW*NH);
    float xf = (float)w, yf = (float)h;
    float depth = depth_hypo[((b*ND + d)*NH + h)*NW + w];

    float wr[NG];
    #pragma unroll
    for (int g = 0; g < NG; ++g) wr[g] = w_reg[g];

    float sv[2], tv[2];

    #pragma unroll
    for (int vv = 0; vv < 2; ++vv) {
        int v = hi + 2*vv;
        const float* RT = pw + (b*NV + v)*12;

        // ---- f32 geometry (mirrors reference's f32 chain) ----
        float rx = RT[0]*xf + RT[1]*yf + RT[2];
        float ry = RT[3]*xf + RT[4]*yf + RT[5];
        float rz = RT[6]*xf + RT[7]*yf + RT[8];
        float px_ = rx*depth + RT[9];
        float py_ = ry*depth + RT[10];
        float pz_ = rz*depth + RT[11];
        if (pz_ == 0.f) pz_ = 1e-9f;
        float iz = 1.0f / pz_;
        float px = px_*iz, py = py_*iz;
        float fx0 = floorf(px), fy0 = floorf(py);
        int x0i = (int)fx0, y0i = (int)fy0;
        int x1i = x0i + 1, y1i = y0i + 1;
        float wx = px - fx0, wy = py - fy0;

        float vx0 = (x0i >= 0 && x0i < NW) ? 1.f : 0.f;
        float vx1 = (x1i >= 0 && x1i < NW) ? 1.f : 0.f;
        float vy0 = (y0i >= 0 && y0i < NH) ? 1.f : 0.f;
        float vy1 = (y1i >= 0 && y1i < NH) ? 1.f : 0.f;
        float w00 = (1.f-wx)*(1.f-wy) * vx0*vy0;
        float w01 = wx*(1.f-wy)       * vx1*vy0;
        float w10 = (1.f-wx)*wy       * vx0*vy1;
        float w11 = wx*wy             * vx1*vy1;
        int xc0 = min(max(x0i,0),NW-1), xc1 = min(max(x1i,0),NW-1);
        int yc0 = min(max(y0i,0),NH-1), yc1 = min(max(y1i,0),NH-1);
        int vb = v*NB + b;

        // ---- bbox butterfly over the half's 32 depths ----
        int mnx = xc0, mxx = xc1, mny = yc0, mxy = yc1;
        #pragma unroll
        for (int mask = 1; mask < 32; mask <<= 1) {
            mnx = min(mnx, __shfl_xor(mnx, mask, 32));
            mxx = max(mxx, __shfl_xor(mxx, mask, 32));
            mny = min(mny, __shfl_xor(mny, mask, 32));
            mxy = max(mxy, __shfl_xor(mxy, mask, 32));
        }
        int bw = mxx - mnx + 1;
        int bh = mxy - mny + 1;
        int U  = bw * bh;

        // ref chunk jme from ORIGINAL layout: 4 scalars at stride HW
        const float* rb = ref_feats + ((size_t)(vb*NC + jme*4))*HW + h*NW + w;
        float s = 0.f, t = 0.f;

        if (U <= QMAX) {
            float4 rfj = make_float4(rb[0], rb[HW], rb[2*HW], rb[3*HW]);
            // ---- phase 1: flattened coalesced element staging ----
            int bw8 = bw * 8;
            int NE  = bh * bw8;
            unsigned int M = (unsigned int)((1u<<22) / (unsigned int)bw8) + 1u;
            int rowstride = NW*NC;
            const float* base = srcT + ((size_t)vb*HW + (size_t)mny*NW + mnx)*NC;
            for (int n = sub; n < NE; n += 32) {
                int row = (int)(((unsigned int)n * M) >> 22);
                int col = n - row*bw8;
                const float4* fp = (const float4*)(base + row*rowstride + col*4);
                float4 f = fp[0];
                float dv = f.x*rfj.x;
                dv = fmaf(f.y, rfj.y, dv);
                dv = fmaf(f.z, rfj.z, dv);
                dv = fmaf(f.w, rfj.w, dv);
                Dh[n] = dv;
            }
            __builtin_amdgcn_wave_barrier();

            // ---- phase 2: compact 8 djs -> (S,T) per q ----
            #pragma unroll
            for (int k = 0; k < 2; ++k) {
                int q = sub + k*32;
                if (q < U) {
                    const float4* dp = (const float4*)&Dh[q*8];
                    float4 a = dp[0], c = dp[1];
                    float S = a.x;  S += a.y;  S += a.z;  S += a.w;
                    S += c.x;  S += c.y;  S += c.z;  S += c.w;
                    float T = wr[0]*a.x;
                    T = fmaf(wr[1], a.y, T);
                    T = fmaf(wr[2], a.z, T);
                    T = fmaf(wr[3], a.w, T);
                    T = fmaf(wr[4], c.x, T);
                    T = fmaf(wr[5], c.y, T);
                    T = fmaf(wr[6], c.z, T);
                    T = fmaf(wr[7], c.w, T);
                    Sh[q] = make_float2(S, T);
                }
            }
            __builtin_amdgcn_wave_barrier();

            // ---- taps ----
            int t00 = (yc0 - mny)*bw + (xc0 - mnx);
            int t01 = (yc0 - mny)*bw + (xc1 - mnx);
            int t10 = (yc1 - mny)*bw + (xc0 - mnx);
            int t11 = (yc1 - mny)*bw + (xc1 - mnx);
            float2 v00 = Sh[t00];
            float2 v01 = Sh[t01];
            float2 v10 = Sh[t10];
            float2 v11 = Sh[t11];
            s = 0.25f*(w00*v00.x + w01*v01.x + w10*v10.x + w11*v11.x);
            t = 0.25f*(w00*v00.y + w01*v01.y + w10*v10.y + w11*v11.y);
        } else {
            // ---- fallback: direct per-depth gathers, ref from original layout ----
            int i00 = yc0*NW+xc0, i01 = yc0*NW+xc1;
            int i10 = yc1*NW+xc0, i11 = yc1*NW+xc1;
            const float4* s00 = (const float4*)(srcT + ((size_t)vb*HW + i00)*NC);
            const float4* s01 = (const float4*)(srcT + ((size_t)vb*HW + i01)*NC);
            const float4* s10 = (const float4*)(srcT + ((size_t)vb*HW + i10)*NC);
            const float4* s11 = (const float4*)(srcT + ((size_t)vb*HW + i11)*NC);
            const float* rbase = ref_feats + (size_t)(vb*NC)*HW + h*NW + w;
            #pragma unroll
            for (int j = 0; j < NG; ++j) {
                float4 a00 = s00[j], a01 = s01[j], a10 = s10[j], a11 = s11[j];
                const float* rj = rbase + (size_t)(j*4)*HW;
                float4 rf = make_float4(rj[0], rj[HW], rj[2*HW], rj[3*HW]);
                float acc = 0.f;
                float f0 = w00*a00.x + w01*a01.x + w10*a10.x + w11*a11.x;
                acc += f0*rf.x;
                float f1 = w00*a00.y + w01*a01.y + w10*a10.y + w11*a11.y;
                acc += f1*rf.y;
                float f2 = w00*a00.z + w01*a01.z + w10*a10.z + w11*a11.z;
                acc += f2*rf.z;
                float f3 = w00*a00.w + w01*a01.w + w10*a10.w + w11*a11.w;
                acc += f3*rf.w;
                float cf = 0.25f*acc;
                s += cf;
                t += cf*wr[j];
            }
        }
        sv[vv] = s; tv[vv] = t;
    }

    // ---- per-view softmax over depths within the half (2-way ILP) ----
    float mv0 = sv[0], mv1 = sv[1];
    #pragma unroll
    for (int mask = 1; mask < 32; mask <<= 1) {
        mv0 = fmaxf(mv0, __shfl_xor(mv0, mask, 32));
        mv1 = fmaxf(mv1, __shfl_xor(mv1, mask, 32));
    }
    float Z0 = expf(sv[0] - mv0);
    float Z1 = expf(sv[1] - mv1);
    #pragma unroll
    for (int mask = 1; mask < 32; mask <<= 1) {
        Z0 += __shfl_xor(Z0, mask, 32);
        Z1 += __shfl_xor(Z1, mask, 32);
    }
    float cwA0 = 1.f / Z0;     // view hi
    float cwA1 = 1.f / Z1;     // view hi+2

    // ---- cross-half exchange; reference-order combine ----
    float cwB0 = __shfl_xor(cwA0, 32, 64);
    float cwB1 = __shfl_xor(cwA1, 32, 64);
    float tB0  = __shfl_xor(tv[0], 32, 64);
    float tB1  = __shfl_xor(tv[1], 32, 64);

    float cwv[NV], tvv[NV];
    if (hi == 0) {   // own v0,v2; other half v1,v3
        cwv[0] = cwA0; tvv[0] = tv[0];
        cwv[1] = cwB0; tvv[1] = tB0;
        cwv[2] = cwA1; tvv[2] = tv[1];
        cwv[3] = cwB1; tvv[3] = tB1;
    } else {          // own v1,v3; other half v0,v2
        cwv[0] = cwB0; tvv[0] = tB0;
        cwv[1] = cwA0; tvv[1] = tv[0];
        cwv[2] = cwB1; tvv[2] = tB1;
        cwv[3] = cwA1; tvv[3] = tv[1];
    }
    float logacc = 0.f;
    float cwsum  = 1e-8f;
    #pragma unroll
    for (int v = 0; v < NV; ++v) {
        logacc += cwv[v]*tvv[v];
        cwsum  += cwv[v];
    }

    float logit = logacc / (cwsum + 1e-7f);
    float m2 = logit;
    #pragma unroll
    for (int mask = 1; mask < 32; mask <<= 1)
        m2 = fmaxf(m2, __shfl_xor(m2, mask, 32));
    float e2 = expf(logit - m2);
    float Z2 = e2;
    #pragma unroll
    for (int mask = 1; mask < 32; mask <<= 1)
        Z2 += __shfl_xor(Z2, mask, 32);
    float aw = e2 / Z2;

    float bv2 = aw; int bi = d;
    #pragma unroll
    for (int mask = 1; mask < 32; mask <<= 1) {
        float ov = __shfl_xor(bv2, mask, 32);
        int   oi = __shfl_xor(bi, mask, 32);
        if (ov > bv2 || (ov == bv2 && oi < bi)) { bv2 = ov; bi = oi; }
    }
    float dsel = __shfl(depth, bi, 32);

    if (hi == 0) {
        out[NPIX + ((b*ND + d)*NH + h)*NW + w] = aw;
        if (d == 0) out[p] = dsel;
    }
}

// ---------------------------------------------------------------------------
// Final fallback (original layout) if ws tiny
// ---------------------------------------------------------------------------
__global__ __launch_bounds__(256) void mvs_kernel(
    const float* __restrict__ ref_feats,
    const float* __restrict__ src_feats,
    const float* __restrict__ depth_hypo,
    const float* __restrict__ w_reg,
    const float* __restrict__ pw,
    float* __restrict__ out)
{
    int tid = blockIdx.x * 256 + threadIdx.x;
    int d = threadIdx.x & 31;
    int p = tid >> 5;
    if (p >= NPIX) return;
    int w = p % NW;
    int h = (p / NW) % NH;
    int b = p / (NW*NH);
    float xf = (float)w, yf = (float)h;
    float depth = depth_hypo[((b*ND + d)*NH + h)*NW + w];
    float wr[NG];
    #pragma unroll
    for (int g = 0; g < NG; ++g) wr[g] = w_reg[g];
    float logacc = 0.f;
    float cwsum  = 1e-8f;
    for (int v = 0; v < NV; ++v) {
        const float* RT = pw + (b*NV + v)*12;
        double dd  = (double)depth;
        double px_ = ((double)RT[0]*(double)xf + (double)RT[1]*(double)yf + (double)RT[2])*dd + (double)RT[9];
        double py_ = ((double)RT[3]*(double)xf + (double)RT[4]*(double)yf + (double)RT[5])*dd + (double)RT[10];
        double pz_ = ((double)RT[6]*(double)xf + (double)RT[7]*(double)yf + (double)RT[8])*dd + (double)RT[11];
        if (pz_ == 0.0) pz_ = 1e-9;
        double iz = 1.0/pz_;
        double pxd = px_*iz, pyd = py_*iz;
        double x0d = floor(pxd), y0d = floor(pyd);
        int x0i = (int)x0d, y0i = (int)y0d;
        int x1i = x0i + 1,  y1i = y0i + 1;
        float wx = (float)(pxd - x0d), wy = (float)(pyd - y0d);
        float vx0 = (x0i >= 0 && x0i < NW) ? 1.f : 0.f;
        float vx1 = (x1i >= 0 && x1i < NW) ? 1.f : 0.f;
        float vy0 = (y0i >= 0 && y0i < NH) ? 1.f : 0.f;
        float vy1 = (y1i >= 0 && y1i < NH) ? 1.f : 0.f;
        float w00 = (1.f-wx)*(1.f-wy) * vx0*vy0;
        float w01 = wx*(1.f-wy)       * vx1*vy0;
        float w10 = (1.f-wx)*wy       * vx0*vy1;
        float w11 = wx*wy             * vx1*vy1;
        int xc0 = min(max(x0i,0),NW-1), xc1 = min(max(x1i,0),NW-1);
        int yc0 = min(max(y0i,0),NH-1), yc1 = min(max(y1i,0),NH-1);
        int i00 = yc0*NW+xc0, i01 = yc0*NW+xc1;
        int i10 = yc1*NW+xc0, i11 = yc1*NW+xc1;
        const float* sb = src_feats + ((v*NB + b)*NC)*HW;
        const float* rb = ref_feats + ((v*NB + b)*NC)*HW + h*NW + w;
        float acc[NG];
        #pragma unroll
        for (int g = 0; g < NG; ++g) acc[g] = 0.f;
        #pragma unroll
        for (int c = 0; c < NC; ++c) {
            const float* scp = sb + c*HW;
            float f = w00*scp[i00] + w01*scp[i01] + w10*scp[i10] + w11*scp[i11];
            acc[c>>2] += f * rb[c*HW];
        }
        float s = 0.f, t = 0.f;
        #pragma unroll
        for (int g = 0; g < NG; ++g) {
            float cf = 0.25f*acc[g];
            s += cf;
            t += cf*wr[g];
        }
        float m = s;
        #pragma unroll
        for (int mask = 1; mask < 32; mask <<= 1)
            m = fmaxf(m, __shfl_xor(m, mask, 32));
        float e = expf(s - m);
        float Z = e;
        #pragma unroll
        for (int mask = 1; mask < 32; mask <<= 1)
            Z += __shfl_xor(Z, mask, 32);
        float cw = 1.f / Z;
        logacc += cw * t;
        cwsum  += cw;
    }
    float logit = logacc / (cwsum + 1e-7f);
    float m2 = logit;
    #pragma unroll
    for (int mask = 1; mask < 32; mask <<= 1)
        m2 = fmaxf(m2, __shfl_xor(m2, mask, 32));
    float e2 = expf(logit - m2);
    float Z2 = e2;
    #pragma unroll
    for (int mask = 1; mask < 32; mask <<= 1)
        Z2 += __shfl_xor(Z2, mask, 32);
    float aw = e2 / Z2;
    out[NPIX + ((b*ND + d)*NH + h)*NW + w] = aw;
    float bv = aw; int bi = d;
    #pragma unroll
    for (int mask = 1; mask < 32; mask <<= 1) {
        float ov = __shfl_xor(bv, mask, 32);
        int   oi = __shfl_xor(bi, mask, 32);
        if (ov > bv || (ov == bv && oi < bi)) { bv = ov; bi = oi; }
    }
    float dsel = __shfl(depth, bi, 32);
    if (d == 0) out[p] = dsel;
}

extern "C" void kernel_launch(void* const* d_in, const int* in_sizes, int n_in,
                              void* d_out, int out_size, void* d_ws, size_t ws_size,
                              hipStream_t stream) {
    const float* ref_feats  = (const float*)d_in[0];
    const float* src_feats  = (const float*)d_in[1];
    const float* proj       = (const float*)d_in[2];
    const float* depth_hypo = (const float*)d_in[3];
    const float* w_reg      = (const float*)d_in[4];
    float* out = (float*)d_out;

    size_t featB = (size_t)FEATSZ*sizeof(float);
    size_t needG = featB + 96*sizeof(float);

    if (ws_size >= needG) {
        char* base = (char*)d_ws;
        float* srcT = (float*)base;                 base += featB;
        float* pw = (float*)base;
        hipLaunchKernelGGL(proj_setup_kernel, dim3(1), dim3(64), 0, stream, proj, pw);
        hipLaunchKernelGGL(prep_kernel, dim3(TGRID), dim3(256), 0, stream,
                           src_feats, srcT);
        hipLaunchKernelGGL(mvs_kernel_g, dim3((NPIX*64)/256), dim3(256), 0, stream,
                           ref_feats, srcT, depth_hypo, w_reg, pw, out);
    } else {
        float* pw = (float*)d_ws;
        hipLaunchKernelGGL(proj_setup_kernel, dim3(1), dim3(64), 0, stream, proj, pw);
        hipLaunchKernelGGL(mvs_kernel, dim3((NPIX*ND)/256), dim3(256), 0, stream,
                           ref_feats, src_feats, depth_hypo, w_reg, pw, out);
    }
}

// Round 16
// 109.912 us; speedup vs baseline: 1.1364x; 1.0088x over previous
//
#include <hip/hip_runtime.h>
#include <math.h>

#define NV 4
#define NB 2
#define NC 32
#define ND 32
#define NH 128
#define NW 160
#define NG 8
#define HW (NH*NW)
#define NPIX (NB*NH*NW)
#define FEATSZ (NV*NB*HW*NC)
#define QMAX 64                // window slots; LDS = 16K (Dsc) + 4K (STl)
#define TBLK (HW/64)
#define TGRID (TBLK*NV*NB)
#define GUARD 0.01f            // >> f32 envelope error (~1.5e-4 px)

// ---------------------------------------------------------------------------
// proj setup (tiny, separate launch) — P = K3@E_src @ inv(K3@E_ref), f64 inverse
// ---------------------------------------------------------------------------
__global__ void proj_setup_kernel(const float* __restrict__ proj,
                                  float* __restrict__ pw) {
    int t = blockIdx.x * blockDim.x + threadIdx.x;
    if (t >= NB * NV) return;
    int b = t / NV, v = t % NV;
    const float* Eref = proj + ((b*(NV+1) + 0)*2 + 0)*16;
    const float* Kref = proj + ((b*(NV+1) + 0)*2 + 1)*16;
    const float* Esrc = proj + ((b*(NV+1) + (v+1))*2 + 0)*16;
    const float* Ksrc = proj + ((b*(NV+1) + (v+1))*2 + 1)*16;
    float Mr[12], Ms[12];
    for (int i = 0; i < 3; ++i)
        for (int j = 0; j < 4; ++j) {
            float sr = 0.f, ss = 0.f;
            for (int k = 0; k < 3; ++k) {
                sr += Kref[i*4+k] * Eref[k*4+j];
                ss += Ksrc[i*4+k] * Esrc[k*4+j];
            }
            Mr[i*4+j] = sr; Ms[i*4+j] = ss;
        }
    double A[9], a[3];
    for (int i = 0; i < 3; ++i) {
        for (int j = 0; j < 3; ++j) A[i*3+j] = (double)Mr[i*4+j];
        a[i] = (double)Mr[i*4+3];
    }
    double c00 = A[4]*A[8]-A[5]*A[7];
    double c01 = A[5]*A[6]-A[3]*A[8];
    double c02 = A[3]*A[7]-A[4]*A[6];
    double det = A[0]*c00 + A[1]*c01 + A[2]*c02;
    double id  = 1.0/det;
    double Ai[9];
    Ai[0]=c00*id;                 Ai[1]=(A[2]*A[7]-A[1]*A[8])*id; Ai[2]=(A[1]*A[5]-A[2]*A[4])*id;
    Ai[3]=c01*id;                 Ai[4]=(A[0]*A[8]-A[2]*A[6])*id; Ai[5]=(A[2]*A[3]-A[0]*A[5])*id;
    Ai[6]=c02*id;                 Ai[7]=(A[1]*A[6]-A[0]*A[7])*id; Ai[8]=(A[0]*A[4]-A[1]*A[3])*id;
    double R[9], T[3];
    for (int i = 0; i < 3; ++i)
        for (int j = 0; j < 3; ++j) {
            double s = 0.0;
            for (int k = 0; k < 3; ++k) s += (double)Ms[i*4+k] * Ai[k*3+j];
            R[i*3+j] = s;
        }
    for (int i = 0; i < 3; ++i) {
        double s = (double)Ms[i*4+3];
        for (int k = 0; k < 3; ++k) s -= R[i*3+k]*a[k];
        T[i] = s;
    }
    float* o = pw + (b*NV + v)*12;
    for (int i = 0; i < 9; ++i) o[i]   = (float)R[i];
    for (int i = 0; i < 3; ++i) o[9+i] = (float)T[i];
}

// ---------------------------------------------------------------------------
// Prep: src transpose ONLY ([vb][c][hw] -> [vb][hw][c])
// ---------------------------------------------------------------------------
__global__ __launch_bounds__(256) void prep_kernel(
    const float* __restrict__ src_feats,
    float* __restrict__ srcT)
{
    __shared__ float lds[NC][65];
    int bid = blockIdx.x;
    int vb = bid / TBLK;
    int hwbase = (bid % TBLK) * 64;
    int t = threadIdx.x;
    #pragma unroll
    for (int r = 0; r < 8; ++r) {
        int c  = (t >> 6) + r*4;
        int hw = t & 63;
        lds[c][hw] = src_feats[(vb*NC + c)*HW + hwbase + hw];
    }
    __syncthreads();
    #pragma unroll
    for (int r = 0; r < 8; ++r) {
        int c  = t & 31;
        int hw = (t >> 5) + r*8;
        srcT[((size_t)vb*HW + hwbase + hw)*NC + c] = lds[c][hw];
    }
}

// ---------------------------------------------------------------------------
// Main: wave = pixel; half hi owns views {hi, hi+2}. f32 in-main geometry.
// Bbox via ENDPOINT PROJECTION (px(d) is Möbius->monotone in d; pz linear so
// equal endpoint signs => no zero crossing; depths are a linspace so lane 0 /
// lane 31 are the extremes). Guard band 0.01px >> f32 envelope error.
// Staging/compaction/taps/softmax/combine identical to R14.
// ---------------------------------------------------------------------------
__global__ __launch_bounds__(256) void mvs_kernel_g(
    const float* __restrict__ ref_feats,
    const float* __restrict__ srcT,
    const float* __restrict__ depth_hypo,
    const float* __restrict__ w_reg,
    const float* __restrict__ pw,
    float* __restrict__ out)
{
    __shared__ float  Dsc[8][QMAX*8];   // 16 KB
    __shared__ float2 STl[8][QMAX];     // 4 KB

    int tid = blockIdx.x * 256 + threadIdx.x;
    int lane = threadIdx.x & 63;
    int d  = lane & 31;
    int hi = lane >> 5;
    int p  = tid >> 6;
    if (p >= NPIX) return;
    int hslot = threadIdx.x >> 5;
    float*  Dh = &Dsc[hslot][0];
    float2* Sh = &STl[hslot][0];
    int sub = lane & 31;
    int jme = sub & 7;

    int w = p % NW;
    int h = (p / NW) % NH;
    int b = p / (NW*NH);
    float xf = (float)w, yf = (float)h;
    float depth = depth_hypo[((b*ND + d)*NH + h)*NW + w];

    // depth endpoints of this half's 32-lane linspace (hoisted out of view loop)
    float dep0  = __shfl(depth, 0, 32);
    float dep31 = __shfl(depth, 31, 32);

    float wr[NG];
    #pragma unroll
    for (int g = 0; g < NG; ++g) wr[g] = w_reg[g];

    float sv[2], tv[2];

    #pragma unroll
    for (int vv = 0; vv < 2; ++vv) {
        int v = hi + 2*vv;
        const float* RT = pw + (b*NV + v)*12;

        // ---- f32 geometry (matches reference's f32 chain) ----
        float rx = RT[0]*xf + RT[1]*yf + RT[2];
        float ry = RT[3]*xf + RT[4]*yf + RT[5];
        float rz = RT[6]*xf + RT[7]*yf + RT[8];
        float px_ = rx*depth + RT[9];
        float py_ = ry*depth + RT[10];
        float pz_ = rz*depth + RT[11];
        if (pz_ == 0.f) pz_ = 1e-9f;
        float iz = 1.0f / pz_;
        float px = px_*iz, py = py_*iz;
        float fx0 = floorf(px), fy0 = floorf(py);
        int x0i = (int)fx0, y0i = (int)fy0;
        int x1i = x0i + 1, y1i = y0i + 1;
        float wx = px - fx0, wy = py - fy0;

        float vx0 = (x0i >= 0 && x0i < NW) ? 1.f : 0.f;
        float vx1 = (x1i >= 0 && x1i < NW) ? 1.f : 0.f;
        float vy0 = (y0i >= 0 && y0i < NH) ? 1.f : 0.f;
        float vy1 = (y1i >= 0 && y1i < NH) ? 1.f : 0.f;
        float w00 = (1.f-wx)*(1.f-wy) * vx0*vy0;
        float w01 = wx*(1.f-wy)       * vx1*vy0;
        float w10 = (1.f-wx)*wy       * vx0*vy1;
        float w11 = wx*wy             * vx1*vy1;
        int xc0 = min(max(x0i,0),NW-1), xc1 = min(max(x1i,0),NW-1);
        int yc0 = min(max(y0i,0),NH-1), yc1 = min(max(y1i,0),NH-1);
        int vb = v*NB + b;

        // ---- endpoint-projection bbox (no butterfly) ----
        float pzA = rz*dep0  + RT[11];
        float pzB = rz*dep31 + RT[11];
        if (pzA == 0.f) pzA = 1e-9f;
        if (pzB == 0.f) pzB = 1e-9f;
        bool ok = (pzA > 0.f) == (pzB > 0.f);
        float izA = 1.0f/pzA, izB = 1.0f/pzB;
        float pxA = (rx*dep0  + RT[9])*izA,  pyA = (ry*dep0  + RT[10])*izA;
        float pxB = (rx*dep31 + RT[9])*izB,  pyB = (ry*dep31 + RT[10])*izB;
        float pxmin = fminf(pxA,pxB) - GUARD, pxmax = fmaxf(pxA,pxB) + GUARD;
        float pymin = fminf(pyA,pyB) - GUARD, pymax = fmaxf(pyA,pyB) + GUARD;
        int mnx = min(max((int)floorf(pxmin), 0), NW-1);
        int mxx = min(max((int)floorf(pxmax) + 1, 0), NW-1);
        int mny = min(max((int)floorf(pymin), 0), NH-1);
        int mxy = min(max((int)floorf(pymax) + 1, 0), NH-1);
        int bw = mxx - mnx + 1;
        int bh = mxy - mny + 1;
        int U  = ok ? (bw * bh) : (QMAX + 1);

        // ref chunk jme from ORIGINAL layout: 4 scalars at stride HW
        const float* rb = ref_feats + ((size_t)(vb*NC + jme*4))*HW + h*NW + w;
        float s = 0.f, t = 0.f;

        if (U <= QMAX) {
            float4 rfj = make_float4(rb[0], rb[HW], rb[2*HW], rb[3*HW]);
            // ---- phase 1: flattened coalesced element staging ----
            int bw8 = bw * 8;
            int NE  = bh * bw8;
            unsigned int M = (unsigned int)((1u<<22) / (unsigned int)bw8) + 1u;
            int rowstride = NW*NC;
            const float* base = srcT + ((size_t)vb*HW + (size_t)mny*NW + mnx)*NC;
            for (int n = sub; n < NE; n += 32) {
                int row = (int)(((unsigned int)n * M) >> 22);
                int col = n - row*bw8;
                const float4* fp = (const float4*)(base + row*rowstride + col*4);
                float4 f = fp[0];
                float dv = f.x*rfj.x;
                dv = fmaf(f.y, rfj.y, dv);
                dv = fmaf(f.z, rfj.z, dv);
                dv = fmaf(f.w, rfj.w, dv);
                Dh[n] = dv;
            }
            __builtin_amdgcn_wave_barrier();

            // ---- phase 2: compact 8 djs -> (S,T) per q ----
            #pragma unroll
            for (int k = 0; k < 2; ++k) {
                int q = sub + k*32;
                if (q < U) {
                    const float4* dp = (const float4*)&Dh[q*8];
                    float4 a = dp[0], c = dp[1];
                    float S = a.x;  S += a.y;  S += a.z;  S += a.w;
                    S += c.x;  S += c.y;  S += c.z;  S += c.w;
                    float T = wr[0]*a.x;
                    T = fmaf(wr[1], a.y, T);
                    T = fmaf(wr[2], a.z, T);
                    T = fmaf(wr[3], a.w, T);
                    T = fmaf(wr[4], c.x, T);
                    T = fmaf(wr[5], c.y, T);
                    T = fmaf(wr[6], c.z, T);
                    T = fmaf(wr[7], c.w, T);
                    Sh[q] = make_float2(S, T);
                }
            }
            __builtin_amdgcn_wave_barrier();

            // ---- taps ----
            int t00 = (yc0 - mny)*bw + (xc0 - mnx);
            int t01 = (yc0 - mny)*bw + (xc1 - mnx);
            int t10 = (yc1 - mny)*bw + (xc0 - mnx);
            int t11 = (yc1 - mny)*bw + (xc1 - mnx);
            float2 v00 = Sh[t00];
            float2 v01 = Sh[t01];
            float2 v10 = Sh[t10];
            float2 v11 = Sh[t11];
            s = 0.25f*(w00*v00.x + w01*v01.x + w10*v10.x + w11*v11.x);
            t = 0.25f*(w00*v00.y + w01*v01.y + w10*v10.y + w11*v11.y);
        } else {
            // ---- fallback: direct per-depth gathers, ref from original layout ----
            int i00 = yc0*NW+xc0, i01 = yc0*NW+xc1;
            int i10 = yc1*NW+xc0, i11 = yc1*NW+xc1;
            const float4* s00 = (const float4*)(srcT + ((size_t)vb*HW + i00)*NC);
            const float4* s01 = (const float4*)(srcT + ((size_t)vb*HW + i01)*NC);
            const float4* s10 = (const float4*)(srcT + ((size_t)vb*HW + i10)*NC);
            const float4* s11 = (const float4*)(srcT + ((size_t)vb*HW + i11)*NC);
            const float* rbase = ref_feats + (size_t)(vb*NC)*HW + h*NW + w;
            #pragma unroll
            for (int j = 0; j < NG; ++j) {
                float4 a00 = s00[j], a01 = s01[j], a10 = s10[j], a11 = s11[j];
                const float* rj = rbase + (size_t)(j*4)*HW;
                float4 rf = make_float4(rj[0], rj[HW], rj[2*HW], rj[3*HW]);
                float acc = 0.f;
                float f0 = w00*a00.x + w01*a01.x + w10*a10.x + w11*a11.x;
                acc += f0*rf.x;
                float f1 = w00*a00.y + w01*a01.y + w10*a10.y + w11*a11.y;
                acc += f1*rf.y;
                float f2 = w00*a00.z + w01*a01.z + w10*a10.z + w11*a11.z;
                acc += f2*rf.z;
                float f3 = w00*a00.w + w01*a01.w + w10*a10.w + w11*a11.w;
                acc += f3*rf.w;
                float cf = 0.25f*acc;
                s += cf;
                t += cf*wr[j];
            }
        }
        sv[vv] = s; tv[vv] = t;
    }

    // ---- per-view softmax over depths within the half (2-way ILP) ----
    float mv0 = sv[0], mv1 = sv[1];
    #pragma unroll
    for (int mask = 1; mask < 32; mask <<= 1) {
        mv0 = fmaxf(mv0, __shfl_xor(mv0, mask, 32));
        mv1 = fmaxf(mv1, __shfl_xor(mv1, mask, 32));
    }
    float Z0 = expf(sv[0] - mv0);
    float Z1 = expf(sv[1] - mv1);
    #pragma unroll
    for (int mask = 1; mask < 32; mask <<= 1) {
        Z0 += __shfl_xor(Z0, mask, 32);
        Z1 += __shfl_xor(Z1, mask, 32);
    }
    float cwA0 = 1.f / Z0;     // view hi
    float cwA1 = 1.f / Z1;     // view hi+2

    // ---- cross-half exchange; reference-order combine ----
    float cwB0 = __shfl_xor(cwA0, 32, 64);
    float cwB1 = __shfl_xor(cwA1, 32, 64);
    float tB0  = __shfl_xor(tv[0], 32, 64);
    float tB1  = __shfl_xor(tv[1], 32, 64);

    float cwv[NV], tvv[NV];
    if (hi == 0) {   // own v0,v2; other half v1,v3
        cwv[0] = cwA0; tvv[0] = tv[0];
        cwv[1] = cwB0; tvv[1] = tB0;
        cwv[2] = cwA1; tvv[2] = tv[1];
        cwv[3] = cwB1; tvv[3] = tB1;
    } else {          // own v1,v3; other half v0,v2
        cwv[0] = cwB0; tvv[0] = tB0;
        cwv[1] = cwA0; tvv[1] = tv[0];
        cwv[2] = cwB1; tvv[2] = tB1;
        cwv[3] = cwA1; tvv[3] = tv[1];
    }
    float logacc = 0.f;
    float cwsum  = 1e-8f;
    #pragma unroll
    for (int v = 0; v < NV; ++v) {
        logacc += cwv[v]*tvv[v];
        cwsum  += cwv[v];
    }

    float logit = logacc / (cwsum + 1e-7f);
    float m2 = logit;
    #pragma unroll
    for (int mask = 1; mask < 32; mask <<= 1)
        m2 = fmaxf(m2, __shfl_xor(m2, mask, 32));
    float e2 = expf(logit - m2);
    float Z2 = e2;
    #pragma unroll
    for (int mask = 1; mask < 32; mask <<= 1)
        Z2 += __shfl_xor(Z2, mask, 32);
    float aw = e2 / Z2;

    float bv2 = aw; int bi = d;
    #pragma unroll
    for (int mask = 1; mask < 32; mask <<= 1) {
        float ov = __shfl_xor(bv2, mask, 32);
        int   oi = __shfl_xor(bi, mask, 32);
        if (ov > bv2 || (ov == bv2 && oi < bi)) { bv2 = ov; bi = oi; }
    }
    float dsel = __shfl(depth, bi, 32);

    if (hi == 0) {
        out[NPIX + ((b*ND + d)*NH + h)*NW + w] = aw;
        if (d == 0) out[p] = dsel;
    }
}

// ---------------------------------------------------------------------------
// Final fallback (original layout) if ws tiny
// ---------------------------------------------------------------------------
__global__ __launch_bounds__(256) void mvs_kernel(
    const float* __restrict__ ref_feats,
    const float* __restrict__ src_feats,
    const float* __restrict__ depth_hypo,
    const float* __restrict__ w_reg,
    const float* __restrict__ pw,
    float* __restrict__ out)
{
    int tid = blockIdx.x * 256 + threadIdx.x;
    int d = threadIdx.x & 31;
    int p = tid >> 5;
    if (p >= NPIX) return;
    int w = p % NW;
    int h = (p / NW) % NH;
    int b = p / (NW*NH);
    float xf = (float)w, yf = (float)h;
    float depth = depth_hypo[((b*ND + d)*NH + h)*NW + w];
    float wr[NG];
    #pragma unroll
    for (int g = 0; g < NG; ++g) wr[g] = w_reg[g];
    float logacc = 0.f;
    float cwsum  = 1e-8f;
    for (int v = 0; v < NV; ++v) {
        const float* RT = pw + (b*NV + v)*12;
        double dd  = (double)depth;
        double px_ = ((double)RT[0]*(double)xf + (double)RT[1]*(double)yf + (double)RT[2])*dd + (double)RT[9];
        double py_ = ((double)RT[3]*(double)xf + (double)RT[4]*(double)yf + (double)RT[5])*dd + (double)RT[10];
        double pz_ = ((double)RT[6]*(double)xf + (double)RT[7]*(double)yf + (double)RT[8])*dd + (double)RT[11];
        if (pz_ == 0.0) pz_ = 1e-9;
        double iz = 1.0/pz_;
        double pxd = px_*iz, pyd = py_*iz;
        double x0d = floor(pxd), y0d = floor(pyd);
        int x0i = (int)x0d, y0i = (int)y0d;
        int x1i = x0i + 1,  y1i = y0i + 1;
        float wx = (float)(pxd - x0d), wy = (float)(pyd - y0d);
        float vx0 = (x0i >= 0 && x0i < NW) ? 1.f : 0.f;
        float vx1 = (x1i >= 0 && x1i < NW) ? 1.f : 0.f;
        float vy0 = (y0i >= 0 && y0i < NH) ? 1.f : 0.f;
        float vy1 = (y1i >= 0 && y1i < NH) ? 1.f : 0.f;
        float w00 = (1.f-wx)*(1.f-wy) * vx0*vy0;
        float w01 = wx*(1.f-wy)       * vx1*vy0;
        float w10 = (1.f-wx)*wy       * vx0*vy1;
        float w11 = wx*wy             * vx1*vy1;
        int xc0 = min(max(x0i,0),NW-1), xc1 = min(max(x1i,0),NW-1);
        int yc0 = min(max(y0i,0),NH-1), yc1 = min(max(y1i,0),NH-1);
        int i00 = yc0*NW+xc0, i01 = yc0*NW+xc1;
        int i10 = yc1*NW+xc0, i11 = yc1*NW+xc1;
        const float* sb = src_feats + ((v*NB + b)*NC)*HW;
        const float* rb = ref_feats + ((v*NB + b)*NC)*HW + h*NW + w;
        float acc[NG];
        #pragma unroll
        for (int g = 0; g < NG; ++g) acc[g] = 0.f;
        #pragma unroll
        for (int c = 0; c < NC; ++c) {
            const float* scp = sb + c*HW;
            float f = w00*scp[i00] + w01*scp[i01] + w10*scp[i10] + w11*scp[i11];
            acc[c>>2] += f * rb[c*HW];
        }
        float s = 0.f, t = 0.f;
        #pragma unroll
        for (int g = 0; g < NG; ++g) {
            float cf = 0.25f*acc[g];
            s += cf;
            t += cf*wr[g];
        }
        float m = s;
        #pragma unroll
        for (int mask = 1; mask < 32; mask <<= 1)
            m = fmaxf(m, __shfl_xor(m, mask, 32));
        float e = expf(s - m);
        float Z = e;
        #pragma unroll
        for (int mask = 1; mask < 32; mask <<= 1)
            Z += __shfl_xor(Z, mask, 32);
        float cw = 1.f / Z;
        logacc += cw * t;
        cwsum  += cw;
    }
    float logit = logacc / (cwsum + 1e-7f);
    float m2 = logit;
    #pragma unroll
    for (int mask = 1; mask < 32; mask <<= 1)
        m2 = fmaxf(m2, __shfl_xor(m2, mask, 32));
    float e2 = expf(logit - m2);
    float Z2 = e2;
    #pragma unroll
    for (int mask = 1; mask < 32; mask <<= 1)
        Z2 += __shfl_xor(Z2, mask, 32);
    float aw = e2 / Z2;
    out[NPIX + ((b*ND + d)*NH + h)*NW + w] = aw;
    float bv = aw; int bi = d;
    #pragma unroll
    for (int mask = 1; mask < 32; mask <<= 1) {
        float ov = __shfl_xor(bv, mask, 32);
        int   oi = __shfl_xor(bi, mask, 32);
        if (ov > bv || (ov == bv && oi < bi)) { bv = ov; bi = oi; }
    }
    float dsel = __shfl(depth, bi, 32);
    if (d == 0) out[p] = dsel;
}

extern "C" void kernel_launch(void* const* d_in, const int* in_sizes, int n_in,
                              void* d_out, int out_size, void* d_ws, size_t ws_size,
                              hipStream_t stream) {
    const float* ref_feats  = (const float*)d_in[0];
    const float* src_feats  = (const float*)d_in[1];
    const float* proj       = (const float*)d_in[2];
    const float* depth_hypo = (const float*)d_in[3];
    const float* w_reg      = (const float*)d_in[4];
    float* out = (float*)d_out;

    size_t featB = (size_t)FEATSZ*sizeof(float);
    size_t needG = featB + 96*sizeof(float);

    if (ws_size >= needG) {
        char* base = (char*)d_ws;
        float* srcT = (float*)base;                 base += featB;
        float* pw = (float*)base;
        hipLaunchKernelGGL(proj_setup_kernel, dim3(1), dim3(64), 0, stream, proj, pw);
        hipLaunchKernelGGL(prep_kernel, dim3(TGRID), dim3(256), 0, stream,
                           src_feats, srcT);
        hipLaunchKernelGGL(mvs_kernel_g, dim3((NPIX*64)/256), dim3(256), 0, stream,
                           ref_feats, srcT, depth_hypo, w_reg, pw, out);
    } else {
        float* pw = (float*)d_ws;
        hipLaunchKernelGGL(proj_setup_kernel, dim3(1), dim3(64), 0, stream, proj, pw);
        hipLaunchKernelGGL(mvs_kernel, dim3((NPIX*ND)/256), dim3(256), 0, stream,
                           ref_feats, src_feats, depth_hypo, w_reg, pw, out);
    }
}